// Round 11
// baseline (270.262 us; speedup 1.0000x reference)
//
#include <hip/hip_runtime.h>

// ---------------------------------------------------------------------------
// MambaBlock fused pipeline, MI355X (gfx950) — round 11
// B=2, L=1024, D_MODEL=1024, D_INNER=2048, D_STATE=16, D_CONV=4, DT_RANK=64
//
// Change vs round 10: gemm_delta launch ELIMINATED. Each scan block computes
// its own 32x256 delta tile via MFMA into LDS (inputs xdbl/wdtT are
// L2-resident; arithmetic bit-identical to the old gemm_delta). 8 -> 7
// dispatches, -48 MB dlt HBM traffic.
// ---------------------------------------------------------------------------

typedef unsigned short u16;
typedef unsigned int   u32;

#define B_SZ 2
#define L_SZ 1024
#define DM   1024
#define DI   2048
#define DS   16
#define DTR  64
#define NXD  96      /* DTR + 2*DS */
#define NCHUNK 32
#define CL   32      /* chunk length: NCHUNK*CL = L */
#define KSPLIT 8     /* split-K for skinny x_dbl GEMM */
#define KC     256   /* 2048 / KSPLIT */

typedef __bf16 bf16x8 __attribute__((ext_vector_type(8)));
typedef float  f32x4  __attribute__((ext_vector_type(4)));

__device__ __forceinline__ u16 f2bf(float f) {
    u32 x = __float_as_uint(f);
    x += 0x7fffu + ((x >> 16) & 1u);   // round-to-nearest-even
    return (u16)(x >> 16);
}
__device__ __forceinline__ float bf2f(u16 v) {
    return __uint_as_float(((u32)v) << 16);
}

__device__ __forceinline__ void gld_lds16(const u16* g, u16* l) {
    __builtin_amdgcn_global_load_lds(
        (const __attribute__((address_space(1))) u32*)g,
        (__attribute__((address_space(3))) u32*)l, 16, 0, 0);
}

// raw workgroup barrier WITHOUT the compiler's vmcnt(0) drain
__device__ __forceinline__ void wg_barrier() {
    __asm__ volatile("" ::: "memory");
    __builtin_amdgcn_s_barrier();
    __asm__ volatile("" ::: "memory");
}
#define WAIT_VM12() __builtin_amdgcn_s_waitcnt(0xF7C)
#define WAIT_VM8()  __builtin_amdgcn_s_waitcnt(0xF78)
#define WAIT_VM6()  __builtin_amdgcn_s_waitcnt(0xF76)
#define WAIT_VM4()  __builtin_amdgcn_s_waitcnt(0xF74)
#define WAIT_VM2()  __builtin_amdgcn_s_waitcnt(0xF72)
#define WAIT_VM0()  __builtin_amdgcn_s_waitcnt(0xF70)

// ---------------------------------------------------------------------------
// Pipelined 128x128 GEMM with XCD swizzle (GEMM1): C = A*BT^T, BK=32,
// 4-buf LDS ring, prefetch distance 3. op==2: Cb bf16 out.
// ---------------------------------------------------------------------------
__global__ __launch_bounds__(256) void gemm128p(
    const u16* __restrict__ A, const u16* __restrict__ BT,
    float* __restrict__ Cf, u16* __restrict__ Cb,
    int M, int N, int K, int op)
{
    __shared__ u16 As[4][128 * 32];
    __shared__ u16 Bs[4][128 * 32];

    const int tid  = threadIdx.x;
    const int wave = tid >> 6;
    const int lane = tid & 63;
    const int q    = lane >> 4;
    const int r16  = lane & 15;
    const int wm   = (wave & 1) * 64;
    const int wn   = (wave >> 1) * 64;
    const int flat = blockIdx.y * 32 + blockIdx.x;
    const int xcd  = flat & 7;
    const int idx  = flat >> 3;
    const int m0   = (idx >> 2) * 128;
    const int n0   = (xcd * 4 + (idx & 3)) * 128;

    const u16* gA0 = A  + (size_t)(m0 + (tid >> 2))      * K + (tid & 3) * 8;
    const u16* gA1 = A  + (size_t)(m0 + 64 + (tid >> 2)) * K + (tid & 3) * 8;
    const u16* gB0 = BT + (size_t)(n0 + (tid >> 2))      * K + (tid & 3) * 8;
    const u16* gB1 = BT + (size_t)(n0 + 64 + (tid >> 2)) * K + (tid & 3) * 8;

    const int niter = K >> 5;
    const int pre = niter < 3 ? niter : 3;
    for (int p = 0; p < pre; ++p) {
        const int k0 = p * 32;
        gld_lds16(gA0 + k0, &As[p][tid * 8]);
        gld_lds16(gA1 + k0, &As[p][2048 + tid * 8]);
        gld_lds16(gB0 + k0, &Bs[p][tid * 8]);
        gld_lds16(gB1 + k0, &Bs[p][2048 + tid * 8]);
    }

    f32x4 acc[4][4];
#pragma unroll
    for (int s = 0; s < 4; ++s)
#pragma unroll
        for (int j = 0; j < 4; ++j) acc[s][j] = (f32x4){0.f, 0.f, 0.f, 0.f};

    for (int it = 0; it < niter; ++it) {
        if (it + 3 < niter) {
            const int k0 = (it + 3) * 32;
            const int bi = (it + 3) & 3;
            gld_lds16(gA0 + k0, &As[bi][tid * 8]);
            gld_lds16(gA1 + k0, &As[bi][2048 + tid * 8]);
            gld_lds16(gB0 + k0, &Bs[bi][tid * 8]);
            gld_lds16(gB1 + k0, &Bs[bi][2048 + tid * 8]);
            WAIT_VM12();
        } else if (it + 2 < niter) {
            WAIT_VM8();
        } else if (it + 1 < niter) {
            WAIT_VM4();
        } else {
            WAIT_VM0();
        }
        wg_barrier();

        const int cur = it & 3;
        bf16x8 af[4], bfr[4];
#pragma unroll
        for (int s = 0; s < 4; ++s)
            af[s] = *(const bf16x8*)(&As[cur][(wm + s * 16 + r16) * 32 + q * 8]);
#pragma unroll
        for (int j = 0; j < 4; ++j)
            bfr[j] = *(const bf16x8*)(&Bs[cur][(wn + j * 16 + r16) * 32 + q * 8]);
#pragma unroll
        for (int s = 0; s < 4; ++s)
#pragma unroll
            for (int j = 0; j < 4; ++j)
                acc[s][j] = __builtin_amdgcn_mfma_f32_16x16x32_bf16(
                    af[s], bfr[j], acc[s][j], 0, 0, 0);

        wg_barrier();
    }

#pragma unroll
    for (int s = 0; s < 4; ++s) {
        const int row0 = m0 + wm + s * 16 + q * 4;
#pragma unroll
        for (int j = 0; j < 4; ++j) {
            const int col = n0 + wn + j * 16 + r16;
            if (op == 2) {
#pragma unroll
                for (int i = 0; i < 4; ++i)
                    Cb[(size_t)(row0 + i) * N + col] = f2bf(acc[s][j][i]);
            } else {
#pragma unroll
                for (int i = 0; i < 4; ++i)
                    Cf[(size_t)(row0 + i) * N + col] = acc[s][j][i];
            }
        }
    }
}

// ---------------------------------------------------------------------------
// GEMM-out: 64x64 tiles, 512 blocks (2/CU), XCD swizzle, direct fp32.
// ---------------------------------------------------------------------------
__global__ __launch_bounds__(256) void gemm_out64(
    const u16* __restrict__ A, const u16* __restrict__ BT,
    float* __restrict__ C, int M, int N, int K)
{
    __shared__ u16 As[4][64 * 32];
    __shared__ u16 Bs[4][64 * 32];

    const int tid  = threadIdx.x;
    const int wave = tid >> 6;
    const int lane = tid & 63;
    const int q    = lane >> 4;
    const int r16  = lane & 15;
    const int wm   = (wave & 1) * 32;
    const int wn   = (wave >> 1) * 32;
    const int flat = blockIdx.y * 16 + blockIdx.x;
    const int xcd  = flat & 7;
    const int idx  = flat >> 3;
    const int n0   = (xcd * 2 + (idx & 1)) * 64;
    const int m0   = (idx >> 1) * 64;

    const u16* gA0 = A  + (size_t)(m0 + (tid >> 2)) * K + (tid & 3) * 8;
    const u16* gB0 = BT + (size_t)(n0 + (tid >> 2)) * K + (tid & 3) * 8;

    const int niter = K >> 5;
    const int pre = niter < 3 ? niter : 3;
    for (int p = 0; p < pre; ++p) {
        const int k0 = p * 32;
        gld_lds16(gA0 + k0, &As[p][tid * 8]);
        gld_lds16(gB0 + k0, &Bs[p][tid * 8]);
    }

    f32x4 acc[2][2];
#pragma unroll
    for (int s = 0; s < 2; ++s)
#pragma unroll
        for (int j = 0; j < 2; ++j) acc[s][j] = (f32x4){0.f, 0.f, 0.f, 0.f};

    for (int it = 0; it < niter; ++it) {
        if (it + 3 < niter) {
            const int k0 = (it + 3) * 32;
            const int bi = (it + 3) & 3;
            gld_lds16(gA0 + k0, &As[bi][tid * 8]);
            gld_lds16(gB0 + k0, &Bs[bi][tid * 8]);
            WAIT_VM6();
        } else if (it + 2 < niter) {
            WAIT_VM4();
        } else if (it + 1 < niter) {
            WAIT_VM2();
        } else {
            WAIT_VM0();
        }
        wg_barrier();

        const int cur = it & 3;
        bf16x8 af[2], bfr[2];
#pragma unroll
        for (int s = 0; s < 2; ++s)
            af[s] = *(const bf16x8*)(&As[cur][(wm + s * 16 + r16) * 32 + q * 8]);
#pragma unroll
        for (int j = 0; j < 2; ++j)
            bfr[j] = *(const bf16x8*)(&Bs[cur][(wn + j * 16 + r16) * 32 + q * 8]);
#pragma unroll
        for (int s = 0; s < 2; ++s)
#pragma unroll
            for (int j = 0; j < 2; ++j)
                acc[s][j] = __builtin_amdgcn_mfma_f32_16x16x32_bf16(
                    af[s], bfr[j], acc[s][j], 0, 0, 0);

        wg_barrier();
    }

#pragma unroll
    for (int s = 0; s < 2; ++s) {
        const int row0 = m0 + wm + s * 16 + q * 4;
#pragma unroll
        for (int j = 0; j < 2; ++j) {
            const int col = n0 + wn + j * 16 + r16;
#pragma unroll
            for (int i = 0; i < 4; ++i)
                C[(size_t)(row0 + i) * N + col] = acc[s][j][i];
        }
    }
}

// ---------------------------------------------------------------------------
// Skinny-N split-K GEMM with FUSED causal conv + silu (proven round 9).
// ---------------------------------------------------------------------------
__global__ __launch_bounds__(256) void gemm_skinny_conv(
    const u16* __restrict__ xzbf, const float* __restrict__ cw,
    const float* __restrict__ cb, const u16* __restrict__ BT,
    float* xdbl, u16* __restrict__ ucbf)
{
    constexpr int LDT = 40;
    __shared__ u16 As[128 * LDT];
    __shared__ u16 Bs[64 * LDT];

    const int tid  = threadIdx.x;
    const int wave = tid >> 6;
    const int lane = tid & 63;
    const int q    = lane >> 4;
    const int r16  = lane & 15;
    const int m0   = blockIdx.y * 128;
    const int n0   = blockIdx.x * 64;
    const int kcs  = blockIdx.z * KC;
    const int sr   = tid >> 2;
    const int ss   = (tid & 3) * 8;

    f32x4 acc[2][4];
#pragma unroll
    for (int s = 0; s < 2; ++s)
#pragma unroll
        for (int j = 0; j < 4; ++j) acc[s][j] = (f32x4){0.f, 0.f, 0.f, 0.f};

    const int bcol  = n0 + sr;
    const int bcolc = bcol < NXD ? bcol : NXD - 1;

    constexpr int NIT = KC / 32;
    for (int it = 0; it < NIT; ++it) {
        const int c = kcs + it * 32 + ss;
        __syncthreads();

        f32x4 cwv[8];
        float cbv[8];
#pragma unroll
        for (int j = 0; j < 8; ++j) {
            cwv[j] = *(const f32x4*)(cw + (size_t)(c + j) * 4);
            cbv[j] = cb[c + j];
        }

        uint4 ua[2];
#pragma unroll
        for (int rsel = 0; rsel < 2; ++rsel) {
            const int r = m0 + rsel * 64 + sr;
            const int l = r & (L_SZ - 1);
            float s8[8];
#pragma unroll
            for (int j = 0; j < 8; ++j) s8[j] = cbv[j];
#pragma unroll
            for (int k = 0; k < 4; ++k) {
                if (l + k - 3 >= 0) {
                    uint4 xv = *(const uint4*)(xzbf + (size_t)(r + k - 3) * (2 * DI) + c);
                    const u16* xp = (const u16*)&xv;
#pragma unroll
                    for (int j = 0; j < 8; ++j) {
                        const float w = (k == 0) ? cwv[j].x : (k == 1) ? cwv[j].y
                                       : (k == 2) ? cwv[j].z : cwv[j].w;
                        s8[j] = fmaf(bf2f(xp[j]), w, s8[j]);
                    }
                }
            }
            u16* up = (u16*)&ua[rsel];
#pragma unroll
            for (int j = 0; j < 8; ++j) {
                float v = s8[j] / (1.f + __expf(-s8[j]));
                up[j] = f2bf(v);
            }
        }
        *(uint4*)(As + sr * LDT + ss)        = ua[0];
        *(uint4*)(As + (64 + sr) * LDT + ss) = ua[1];
        if (n0 == 0) {
            *(uint4*)(ucbf + (size_t)(m0 + sr) * DI + c)      = ua[0];
            *(uint4*)(ucbf + (size_t)(m0 + 64 + sr) * DI + c) = ua[1];
        }
        *(uint4*)(Bs + sr * LDT + ss) =
            *(const uint4*)(BT + (size_t)bcolc * DI + kcs + it * 32 + ss);
        __syncthreads();

        bf16x8 af[2], bfr[4];
#pragma unroll
        for (int s = 0; s < 2; ++s)
            af[s] = *(const bf16x8*)(As + (wave * 32 + s * 16 + r16) * LDT + q * 8);
#pragma unroll
        for (int j = 0; j < 4; ++j)
            bfr[j] = *(const bf16x8*)(Bs + (j * 16 + r16) * LDT + q * 8);
#pragma unroll
        for (int s = 0; s < 2; ++s)
#pragma unroll
            for (int j = 0; j < 4; ++j)
                acc[s][j] = __builtin_amdgcn_mfma_f32_16x16x32_bf16(
                    af[s], bfr[j], acc[s][j], 0, 0, 0);
    }

#pragma unroll
    for (int s = 0; s < 2; ++s) {
        const int row0 = m0 + wave * 32 + s * 16 + q * 4;
#pragma unroll
        for (int j = 0; j < 4; ++j) {
            const int col = n0 + j * 16 + r16;
            if (col < NXD) {
#pragma unroll
                for (int i = 0; i < 4; ++i)
                    atomicAdd(&xdbl[(size_t)(row0 + i) * NXD + col], acc[s][j][i]);
            }
        }
    }
}

// ---------------------------------------------------------------------------
// fused prep: x cast + 4 weight transposes + zero xdbl (for atomics)
// ---------------------------------------------------------------------------
__device__ __forceinline__ void tr_tile(
    const float* __restrict__ in, u16* __restrict__ out,
    int R, int C, int tr, int tc, int tid, float (*t)[33])
{
    const int tx = tid & 31, ty = tid >> 5;
    const int r0 = tr * 32, c0 = tc * 32;
#pragma unroll
    for (int i = 0; i < 4; ++i) {
        int r = r0 + ty + i * 8, c = c0 + tx;
        if (r < R && c < C) t[ty + i * 8][tx] = in[(size_t)r * C + c];
    }
    __syncthreads();
#pragma unroll
    for (int i = 0; i < 4; ++i) {
        int oR = c0 + ty + i * 8, oC = r0 + tx;
        if (oR < C && oC < R) out[(size_t)oR * R + oC] = f2bf(t[tx][ty + i * 8]);
    }
}

__global__ __launch_bounds__(256) void prep_kernel(
    const float* __restrict__ x,     u16* __restrict__ xbf,
    const float* __restrict__ W_in,  u16* __restrict__ winT,
    const float* __restrict__ W_out, u16* __restrict__ woutT,
    const float* __restrict__ W_x,   u16* __restrict__ wxT,
    const float* __restrict__ W_dt,  u16* __restrict__ wdtT,
    float* __restrict__ xdbl)
{
    __shared__ float t[32][33];
    const int id  = blockIdx.x;
    const int tid = threadIdx.x;
    if (id < 4096) {                                   // W_in: 1024x4096
        tr_tile(W_in, winT, 1024, 4096, id >> 7, id & 127, tid, t);
    } else if (id < 6144) {                            // W_out: 2048x1024
        int i2 = id - 4096;
        tr_tile(W_out, woutT, 2048, 1024, i2 >> 5, i2 & 31, tid, t);
    } else if (id < 6336) {                            // W_x: 2048x96
        int i3 = id - 6144;
        tr_tile(W_x, wxT, 2048, 96, i3 / 3, i3 % 3, tid, t);
    } else if (id < 6464) {                            // W_dt: 64x2048
        int i4 = id - 6336;
        tr_tile(W_dt, wdtT, 64, 2048, i4 >> 6, i4 & 63, tid, t);
    } else if (id < 14656) {                           // x cast: 2,097,152
        int i = (id - 6464) * 256 + tid;
        xbf[i] = f2bf(x[i]);
    } else {                                           // zero xdbl: 196,608 f
        f32x4 z = (f32x4){0.f, 0.f, 0.f, 0.f};
        ((f32x4*)xdbl)[(size_t)(id - 14656) * 256 + tid] = z;
    }
}

// ---------------------------------------------------------------------------
// Per-block delta tile: dl[32][256] = softplus(xdbl[rows, :64] @ W_dt + b_dt)
// M=32, N=256, K=64 via 64 MFMAs. Arithmetic bit-identical to old gemm_delta
// (same f2bf casts, same MFMA k-order, same bias+softplus).
// Wave w computes n-tiles [w*4, w*4+4); columns [w*64,(w+1)*64) — each thread
// later reads only its own wave's columns (col = tid).
// ---------------------------------------------------------------------------
__device__ __forceinline__ void compute_delta_tile(
    const float* __restrict__ xdbl, const u16* __restrict__ wdtT,
    const float* __restrict__ b_dt, int rowbase, int d0, int tid,
    float (*dl)[256])
{
    const int wave = tid >> 6;
    const int lane = tid & 63;
    const int q    = lane >> 4;
    const int r16  = lane & 15;

    f32x4 dacc[2][4];
#pragma unroll
    for (int mt = 0; mt < 2; ++mt)
#pragma unroll
        for (int nt = 0; nt < 4; ++nt) dacc[mt][nt] = (f32x4){0.f, 0.f, 0.f, 0.f};

#pragma unroll
    for (int ks = 0; ks < 2; ++ks) {
        bf16x8 afr[2];
#pragma unroll
        for (int mt = 0; mt < 2; ++mt) {
            const float* ap = xdbl + (size_t)(rowbase + mt * 16 + r16) * NXD + ks * 32 + q * 8;
            f32x4 a0 = *(const f32x4*)ap;
            f32x4 a1 = *(const f32x4*)(ap + 4);
            union { u16 u[8]; bf16x8 v; } cvt;
#pragma unroll
            for (int i = 0; i < 4; ++i) { cvt.u[i] = f2bf(a0[i]); cvt.u[4 + i] = f2bf(a1[i]); }
            afr[mt] = cvt.v;
        }
#pragma unroll
        for (int nt = 0; nt < 4; ++nt) {
            const u16* bp = wdtT + (size_t)(d0 + (wave * 4 + nt) * 16 + r16) * DTR + ks * 32 + q * 8;
            bf16x8 bfr = *(const bf16x8*)bp;
#pragma unroll
            for (int mt = 0; mt < 2; ++mt)
                dacc[mt][nt] = __builtin_amdgcn_mfma_f32_16x16x32_bf16(
                    afr[mt], bfr, dacc[mt][nt], 0, 0, 0);
        }
    }

#pragma unroll
    for (int mt = 0; mt < 2; ++mt)
#pragma unroll
        for (int nt = 0; nt < 4; ++nt) {
            const int colg = (wave * 4 + nt) * 16 + r16;   // 0..255 in-block
            const float bv = b_dt[d0 + colg];
#pragma unroll
            for (int i = 0; i < 4; ++i) {
                float v = dacc[mt][nt][i] + bv;
                v = (v > 20.f) ? v : log1pf(__expf(v));
                dl[mt * 16 + q * 4 + i][colg] = v;
            }
        }
}

// ---------------------------------------------------------------------------
// Selective scan, 3-pass chunked, NCHUNK=32; delta computed in-block (LDS).
// ---------------------------------------------------------------------------
__global__ __launch_bounds__(256) void scan_pass1(
    const u16* __restrict__ ucbf, const float* __restrict__ xdbl,
    const u16* __restrict__ wdtT, const float* __restrict__ b_dt,
    const float* __restrict__ A_log,
    float* __restrict__ hbuf, float* __restrict__ pbuf)
{
    __shared__ float dl[CL][256];   // 32 KB
    const int c = blockIdx.x;
    const int g = blockIdx.y;
    const int b = blockIdx.z;
    const int tid = threadIdx.x;
    const int d = g * 256 + tid;
    const int rowbase = b * L_SZ + c * CL;

    compute_delta_tile(xdbl, wdtT, b_dt, rowbase, g * 256, tid, dl);
    __syncthreads();

    float Av[16], h[16], P[16];
#pragma unroll
    for (int n = 0; n < 16; ++n) {
        Av[n] = -__expf(A_log[d * 16 + n]);
        h[n] = 0.f; P[n] = 1.f;
    }
    for (int i = 0; i < CL; ++i) {
        const int row = rowbase + i;
        float dlt = dl[i][tid];
        float uu  = bf2f(ucbf[(size_t)row * DI + d]);
        float du  = dlt * uu;
        const float* xr = xdbl + (size_t)row * NXD;   // block-uniform address
#pragma unroll
        for (int n = 0; n < 16; ++n) {
            float e = __expf(dlt * Av[n]);
            P[n] *= e;
            h[n] = fmaf(e, h[n], du * xr[DTR + n]);
        }
    }
    size_t base = ((size_t)((b * NCHUNK + c) * DI + d)) * 16;
#pragma unroll
    for (int n = 0; n < 16; ++n) { hbuf[base + n] = h[n]; pbuf[base + n] = P[n]; }
}

// parallel over (b, d*16+n): coalesced
__global__ __launch_bounds__(256) void scan_pass2(
    float* __restrict__ hbuf, const float* __restrict__ pbuf)
{
    const int j = blockIdx.x * 256 + threadIdx.x;   // d*16+n in [0, 32768)
    const int b = blockIdx.y;
    float h0 = 0.f;
    for (int cc = 0; cc < NCHUNK; ++cc) {
        size_t o = ((size_t)(b * NCHUNK + cc)) * (DI * 16) + j;
        float hl = hbuf[o];
        float Pl = pbuf[o];
        hbuf[o] = h0;                  // h0 entering chunk cc
        h0 = fmaf(Pl, h0, hl);
    }
}

__global__ __launch_bounds__(256) void scan_pass3(
    const u16* __restrict__ ucbf, const float* __restrict__ xdbl,
    const u16* __restrict__ wdtT, const float* __restrict__ b_dt,
    const float* __restrict__ A_log, const float* __restrict__ hbuf,
    const u16* __restrict__ xzbf, const float* __restrict__ Dskip,
    u16* __restrict__ ybf)
{
    __shared__ float dl[CL][256];   // 32 KB
    const int c = blockIdx.x;
    const int g = blockIdx.y;
    const int b = blockIdx.z;
    const int tid = threadIdx.x;
    const int d = g * 256 + tid;
    const int rowbase = b * L_SZ + c * CL;

    compute_delta_tile(xdbl, wdtT, b_dt, rowbase, g * 256, tid, dl);
    __syncthreads();

    float Av[16], h[16];
    size_t base = ((size_t)((b * NCHUNK + c) * DI + d)) * 16;
#pragma unroll
    for (int n = 0; n < 16; ++n) {
        Av[n] = -__expf(A_log[d * 16 + n]);
        h[n]  = hbuf[base + n];
    }
    const float Dk = Dskip[d];
    for (int i = 0; i < CL; ++i) {
        const int row = rowbase + i;
        float dlt = dl[i][tid];
        float uu  = bf2f(ucbf[(size_t)row * DI + d]);
        float du  = dlt * uu;
        const float* xr = xdbl + (size_t)row * NXD;
        float y = 0.f;
#pragma unroll
        for (int n = 0; n < 16; ++n) {
            float e = __expf(dlt * Av[n]);
            h[n] = fmaf(e, h[n], du * xr[DTR + n]);
            y = fmaf(h[n], xr[DTR + DS + n], y);
        }
        float zz = bf2f(xzbf[(size_t)row * (2 * DI) + DI + d]);
        float yv = fmaf(uu, Dk, y) * (zz / (1.f + __expf(-zz)));
        ybf[(size_t)row * DI + d] = f2bf(yv);
    }
}

// ---------------------------------------------------------------------------
// workspace layout (f32 element offsets) — dlt eliminated
// ---------------------------------------------------------------------------
constexpr size_t OFF_XDBL    = 0;                          //   196,608 f
constexpr size_t OFF_HBUF    = OFF_XDBL + 196608;          // 2,097,152 f
constexpr size_t OFF_PBUF    = OFF_HBUF + 2097152;         // 2,097,152 f
constexpr size_t OFF_F32_END = OFF_PBUF + 2097152;
// bf16 region (u16 offsets from end of fp32 region)
constexpr size_t SOFF_XBF   = 0;                     // 2,097,152
constexpr size_t SOFF_WINT  = SOFF_XBF   + 2097152;  // 4,194,304
constexpr size_t SOFF_XZBF  = SOFF_WINT  + 4194304;  // 8,388,608
constexpr size_t SOFF_UCBF  = SOFF_XZBF  + 8388608;  // 4,194,304
constexpr size_t SOFF_WXT   = SOFF_UCBF  + 4194304;  //   196,608
constexpr size_t SOFF_WDTT  = SOFF_WXT   + 196608;   //   131,072
constexpr size_t SOFF_WOUTT = SOFF_WDTT  + 131072;   // 2,097,152
constexpr size_t SOFF_YBF   = SOFF_WOUTT + 2097152;  // 4,194,304

extern "C" void kernel_launch(void* const* d_in, const int* in_sizes, int n_in,
                              void* d_out, int out_size, void* d_ws, size_t ws_size,
                              hipStream_t stream)
{
    const float* x     = (const float*)d_in[0];
    const float* W_in  = (const float*)d_in[1];
    const float* cw    = (const float*)d_in[2];
    const float* cb    = (const float*)d_in[3];
    const float* W_x   = (const float*)d_in[4];
    const float* W_dt  = (const float*)d_in[5];
    const float* b_dt  = (const float*)d_in[6];
    const float* A_log = (const float*)d_in[7];
    const float* Dsk   = (const float*)d_in[8];
    const float* W_out = (const float*)d_in[9];
    float* out = (float*)d_out;

    float* wsf   = (float*)d_ws;
    float* xdbl  = wsf + OFF_XDBL;
    float* hbuf  = wsf + OFF_HBUF;
    float* pbuf  = wsf + OFF_PBUF;
    u16* sb    = (u16*)(wsf + OFF_F32_END);
    u16* xbf   = sb + SOFF_XBF;
    u16* winT  = sb + SOFF_WINT;
    u16* xzbf  = sb + SOFF_XZBF;
    u16* ucbf  = sb + SOFF_UCBF;
    u16* wxT   = sb + SOFF_WXT;
    u16* wdtT  = sb + SOFF_WDTT;
    u16* woutT = sb + SOFF_WOUTT;
    u16* ybf   = sb + SOFF_YBF;

    // 1) fused prep (casts, transposes, xdbl zero)
    prep_kernel<<<14848, 256, 0, stream>>>(x, xbf, W_in, winT, W_out, woutT,
                                           W_x, wxT, W_dt, wdtT, xdbl);

    // 2) xz = x @ W_in  (M=2048, N=4096, K=1024) -> bf16, XCD-swizzled
    gemm128p<<<dim3(32, 16), 256, 0, stream>>>(
        xbf, winT, nullptr, xzbf, 2048, 4096, 1024, 2);

    // 3) x_dbl = silu(conv(xz)) @ W_x — conv fused into staging; atomics to xdbl
    gemm_skinny_conv<<<dim3(2, 16, KSPLIT), 256, 0, stream>>>(
        xzbf, cw, cb, wxT, xdbl, ucbf);

    // 4) selective scan (3 launches; delta computed in-block via MFMA)
    scan_pass1<<<dim3(NCHUNK, DI / 256, B_SZ), 256, 0, stream>>>(
        ucbf, xdbl, wdtT, b_dt, A_log, hbuf, pbuf);
    scan_pass2<<<dim3(DI * 16 / 256, B_SZ), 256, 0, stream>>>(hbuf, pbuf);
    scan_pass3<<<dim3(NCHUNK, DI / 256, B_SZ), 256, 0, stream>>>(
        ucbf, xdbl, wdtT, b_dt, A_log, hbuf, xzbf, Dsk, ybf);

    // 5) out = y @ W_out  (M=2048, N=1024, K=2048) — 64x64 tiles, 2 blocks/CU
    gemm_out64<<<dim3(16, 32), 256, 0, stream>>>(ybf, woutT, out, 2048, 1024, 2048);
}

// Round 12
// 264.012 us; speedup vs baseline: 1.0237x; 1.0237x over previous
//
#include <hip/hip_runtime.h>

// ---------------------------------------------------------------------------
// MambaBlock fused pipeline, MI355X (gfx950) — round 12
// B=2, L=1024, D_MODEL=1024, D_INNER=2048, D_STATE=16, D_CONV=4, DT_RANK=64
//
// Round 11 exposed the scans: pass1 = 44 µs at Occupancy 16% (512 blocks =
// 2/CU), VALUBusy 46%. Changes (scan-only):
//  * NCHUNK 32 -> 64 (CL=16): 1024 blocks = 4/CU = 16 waves/CU.
//  * software-prefetch u/B/C rows inside the scan loops (hide L2 latency
//    behind the 16-exp VALU burst).
//  * delta LDS tile 32 KB -> 16 KB (16 rows).
// Everything else identical to round 11.
// ---------------------------------------------------------------------------

typedef unsigned short u16;
typedef unsigned int   u32;

#define B_SZ 2
#define L_SZ 1024
#define DM   1024
#define DI   2048
#define DS   16
#define DTR  64
#define NXD  96      /* DTR + 2*DS */
#define NCHUNK 64
#define CL   16      /* chunk length: NCHUNK*CL = L */
#define KSPLIT 8     /* split-K for skinny x_dbl GEMM */
#define KC     256   /* 2048 / KSPLIT */

typedef __bf16 bf16x8 __attribute__((ext_vector_type(8)));
typedef float  f32x4  __attribute__((ext_vector_type(4)));

__device__ __forceinline__ u16 f2bf(float f) {
    u32 x = __float_as_uint(f);
    x += 0x7fffu + ((x >> 16) & 1u);   // round-to-nearest-even
    return (u16)(x >> 16);
}
__device__ __forceinline__ float bf2f(u16 v) {
    return __uint_as_float(((u32)v) << 16);
}

__device__ __forceinline__ void gld_lds16(const u16* g, u16* l) {
    __builtin_amdgcn_global_load_lds(
        (const __attribute__((address_space(1))) u32*)g,
        (__attribute__((address_space(3))) u32*)l, 16, 0, 0);
}

// raw workgroup barrier WITHOUT the compiler's vmcnt(0) drain
__device__ __forceinline__ void wg_barrier() {
    __asm__ volatile("" ::: "memory");
    __builtin_amdgcn_s_barrier();
    __asm__ volatile("" ::: "memory");
}
#define WAIT_VM12() __builtin_amdgcn_s_waitcnt(0xF7C)
#define WAIT_VM8()  __builtin_amdgcn_s_waitcnt(0xF78)
#define WAIT_VM6()  __builtin_amdgcn_s_waitcnt(0xF76)
#define WAIT_VM4()  __builtin_amdgcn_s_waitcnt(0xF74)
#define WAIT_VM2()  __builtin_amdgcn_s_waitcnt(0xF72)
#define WAIT_VM0()  __builtin_amdgcn_s_waitcnt(0xF70)

// ---------------------------------------------------------------------------
// Pipelined 128x128 GEMM with XCD swizzle (GEMM1): C = A*BT^T, BK=32,
// 4-buf LDS ring, prefetch distance 3. op==2: Cb bf16 out.
// ---------------------------------------------------------------------------
__global__ __launch_bounds__(256) void gemm128p(
    const u16* __restrict__ A, const u16* __restrict__ BT,
    float* __restrict__ Cf, u16* __restrict__ Cb,
    int M, int N, int K, int op)
{
    __shared__ u16 As[4][128 * 32];
    __shared__ u16 Bs[4][128 * 32];

    const int tid  = threadIdx.x;
    const int wave = tid >> 6;
    const int lane = tid & 63;
    const int q    = lane >> 4;
    const int r16  = lane & 15;
    const int wm   = (wave & 1) * 64;
    const int wn   = (wave >> 1) * 64;
    const int flat = blockIdx.y * 32 + blockIdx.x;
    const int xcd  = flat & 7;
    const int idx  = flat >> 3;
    const int m0   = (idx >> 2) * 128;
    const int n0   = (xcd * 4 + (idx & 3)) * 128;

    const u16* gA0 = A  + (size_t)(m0 + (tid >> 2))      * K + (tid & 3) * 8;
    const u16* gA1 = A  + (size_t)(m0 + 64 + (tid >> 2)) * K + (tid & 3) * 8;
    const u16* gB0 = BT + (size_t)(n0 + (tid >> 2))      * K + (tid & 3) * 8;
    const u16* gB1 = BT + (size_t)(n0 + 64 + (tid >> 2)) * K + (tid & 3) * 8;

    const int niter = K >> 5;
    const int pre = niter < 3 ? niter : 3;
    for (int p = 0; p < pre; ++p) {
        const int k0 = p * 32;
        gld_lds16(gA0 + k0, &As[p][tid * 8]);
        gld_lds16(gA1 + k0, &As[p][2048 + tid * 8]);
        gld_lds16(gB0 + k0, &Bs[p][tid * 8]);
        gld_lds16(gB1 + k0, &Bs[p][2048 + tid * 8]);
    }

    f32x4 acc[4][4];
#pragma unroll
    for (int s = 0; s < 4; ++s)
#pragma unroll
        for (int j = 0; j < 4; ++j) acc[s][j] = (f32x4){0.f, 0.f, 0.f, 0.f};

    for (int it = 0; it < niter; ++it) {
        if (it + 3 < niter) {
            const int k0 = (it + 3) * 32;
            const int bi = (it + 3) & 3;
            gld_lds16(gA0 + k0, &As[bi][tid * 8]);
            gld_lds16(gA1 + k0, &As[bi][2048 + tid * 8]);
            gld_lds16(gB0 + k0, &Bs[bi][tid * 8]);
            gld_lds16(gB1 + k0, &Bs[bi][2048 + tid * 8]);
            WAIT_VM12();
        } else if (it + 2 < niter) {
            WAIT_VM8();
        } else if (it + 1 < niter) {
            WAIT_VM4();
        } else {
            WAIT_VM0();
        }
        wg_barrier();

        const int cur = it & 3;
        bf16x8 af[4], bfr[4];
#pragma unroll
        for (int s = 0; s < 4; ++s)
            af[s] = *(const bf16x8*)(&As[cur][(wm + s * 16 + r16) * 32 + q * 8]);
#pragma unroll
        for (int j = 0; j < 4; ++j)
            bfr[j] = *(const bf16x8*)(&Bs[cur][(wn + j * 16 + r16) * 32 + q * 8]);
#pragma unroll
        for (int s = 0; s < 4; ++s)
#pragma unroll
            for (int j = 0; j < 4; ++j)
                acc[s][j] = __builtin_amdgcn_mfma_f32_16x16x32_bf16(
                    af[s], bfr[j], acc[s][j], 0, 0, 0);

        wg_barrier();
    }

#pragma unroll
    for (int s = 0; s < 4; ++s) {
        const int row0 = m0 + wm + s * 16 + q * 4;
#pragma unroll
        for (int j = 0; j < 4; ++j) {
            const int col = n0 + wn + j * 16 + r16;
            if (op == 2) {
#pragma unroll
                for (int i = 0; i < 4; ++i)
                    Cb[(size_t)(row0 + i) * N + col] = f2bf(acc[s][j][i]);
            } else {
#pragma unroll
                for (int i = 0; i < 4; ++i)
                    Cf[(size_t)(row0 + i) * N + col] = acc[s][j][i];
            }
        }
    }
}

// ---------------------------------------------------------------------------
// GEMM-out: 64x64 tiles, 512 blocks (2/CU), XCD swizzle, direct fp32.
// ---------------------------------------------------------------------------
__global__ __launch_bounds__(256) void gemm_out64(
    const u16* __restrict__ A, const u16* __restrict__ BT,
    float* __restrict__ C, int M, int N, int K)
{
    __shared__ u16 As[4][64 * 32];
    __shared__ u16 Bs[4][64 * 32];

    const int tid  = threadIdx.x;
    const int wave = tid >> 6;
    const int lane = tid & 63;
    const int q    = lane >> 4;
    const int r16  = lane & 15;
    const int wm   = (wave & 1) * 32;
    const int wn   = (wave >> 1) * 32;
    const int flat = blockIdx.y * 16 + blockIdx.x;
    const int xcd  = flat & 7;
    const int idx  = flat >> 3;
    const int n0   = (xcd * 2 + (idx & 1)) * 64;
    const int m0   = (idx >> 1) * 64;

    const u16* gA0 = A  + (size_t)(m0 + (tid >> 2)) * K + (tid & 3) * 8;
    const u16* gB0 = BT + (size_t)(n0 + (tid >> 2)) * K + (tid & 3) * 8;

    const int niter = K >> 5;
    const int pre = niter < 3 ? niter : 3;
    for (int p = 0; p < pre; ++p) {
        const int k0 = p * 32;
        gld_lds16(gA0 + k0, &As[p][tid * 8]);
        gld_lds16(gB0 + k0, &Bs[p][tid * 8]);
    }

    f32x4 acc[2][2];
#pragma unroll
    for (int s = 0; s < 2; ++s)
#pragma unroll
        for (int j = 0; j < 2; ++j) acc[s][j] = (f32x4){0.f, 0.f, 0.f, 0.f};

    for (int it = 0; it < niter; ++it) {
        if (it + 3 < niter) {
            const int k0 = (it + 3) * 32;
            const int bi = (it + 3) & 3;
            gld_lds16(gA0 + k0, &As[bi][tid * 8]);
            gld_lds16(gB0 + k0, &Bs[bi][tid * 8]);
            WAIT_VM6();
        } else if (it + 2 < niter) {
            WAIT_VM4();
        } else if (it + 1 < niter) {
            WAIT_VM2();
        } else {
            WAIT_VM0();
        }
        wg_barrier();

        const int cur = it & 3;
        bf16x8 af[2], bfr[2];
#pragma unroll
        for (int s = 0; s < 2; ++s)
            af[s] = *(const bf16x8*)(&As[cur][(wm + s * 16 + r16) * 32 + q * 8]);
#pragma unroll
        for (int j = 0; j < 2; ++j)
            bfr[j] = *(const bf16x8*)(&Bs[cur][(wn + j * 16 + r16) * 32 + q * 8]);
#pragma unroll
        for (int s = 0; s < 2; ++s)
#pragma unroll
            for (int j = 0; j < 2; ++j)
                acc[s][j] = __builtin_amdgcn_mfma_f32_16x16x32_bf16(
                    af[s], bfr[j], acc[s][j], 0, 0, 0);

        wg_barrier();
    }

#pragma unroll
    for (int s = 0; s < 2; ++s) {
        const int row0 = m0 + wm + s * 16 + q * 4;
#pragma unroll
        for (int j = 0; j < 2; ++j) {
            const int col = n0 + wn + j * 16 + r16;
#pragma unroll
            for (int i = 0; i < 4; ++i)
                C[(size_t)(row0 + i) * N + col] = acc[s][j][i];
        }
    }
}

// ---------------------------------------------------------------------------
// Skinny-N split-K GEMM with FUSED causal conv + silu (proven round 9).
// ---------------------------------------------------------------------------
__global__ __launch_bounds__(256) void gemm_skinny_conv(
    const u16* __restrict__ xzbf, const float* __restrict__ cw,
    const float* __restrict__ cb, const u16* __restrict__ BT,
    float* xdbl, u16* __restrict__ ucbf)
{
    constexpr int LDT = 40;
    __shared__ u16 As[128 * LDT];
    __shared__ u16 Bs[64 * LDT];

    const int tid  = threadIdx.x;
    const int wave = tid >> 6;
    const int lane = tid & 63;
    const int q    = lane >> 4;
    const int r16  = lane & 15;
    const int m0   = blockIdx.y * 128;
    const int n0   = blockIdx.x * 64;
    const int kcs  = blockIdx.z * KC;
    const int sr   = tid >> 2;
    const int ss   = (tid & 3) * 8;

    f32x4 acc[2][4];
#pragma unroll
    for (int s = 0; s < 2; ++s)
#pragma unroll
        for (int j = 0; j < 4; ++j) acc[s][j] = (f32x4){0.f, 0.f, 0.f, 0.f};

    const int bcol  = n0 + sr;
    const int bcolc = bcol < NXD ? bcol : NXD - 1;

    constexpr int NIT = KC / 32;
    for (int it = 0; it < NIT; ++it) {
        const int c = kcs + it * 32 + ss;
        __syncthreads();

        f32x4 cwv[8];
        float cbv[8];
#pragma unroll
        for (int j = 0; j < 8; ++j) {
            cwv[j] = *(const f32x4*)(cw + (size_t)(c + j) * 4);
            cbv[j] = cb[c + j];
        }

        uint4 ua[2];
#pragma unroll
        for (int rsel = 0; rsel < 2; ++rsel) {
            const int r = m0 + rsel * 64 + sr;
            const int l = r & (L_SZ - 1);
            float s8[8];
#pragma unroll
            for (int j = 0; j < 8; ++j) s8[j] = cbv[j];
#pragma unroll
            for (int k = 0; k < 4; ++k) {
                if (l + k - 3 >= 0) {
                    uint4 xv = *(const uint4*)(xzbf + (size_t)(r + k - 3) * (2 * DI) + c);
                    const u16* xp = (const u16*)&xv;
#pragma unroll
                    for (int j = 0; j < 8; ++j) {
                        const float w = (k == 0) ? cwv[j].x : (k == 1) ? cwv[j].y
                                       : (k == 2) ? cwv[j].z : cwv[j].w;
                        s8[j] = fmaf(bf2f(xp[j]), w, s8[j]);
                    }
                }
            }
            u16* up = (u16*)&ua[rsel];
#pragma unroll
            for (int j = 0; j < 8; ++j) {
                float v = s8[j] / (1.f + __expf(-s8[j]));
                up[j] = f2bf(v);
            }
        }
        *(uint4*)(As + sr * LDT + ss)        = ua[0];
        *(uint4*)(As + (64 + sr) * LDT + ss) = ua[1];
        if (n0 == 0) {
            *(uint4*)(ucbf + (size_t)(m0 + sr) * DI + c)      = ua[0];
            *(uint4*)(ucbf + (size_t)(m0 + 64 + sr) * DI + c) = ua[1];
        }
        *(uint4*)(Bs + sr * LDT + ss) =
            *(const uint4*)(BT + (size_t)bcolc * DI + kcs + it * 32 + ss);
        __syncthreads();

        bf16x8 af[2], bfr[4];
#pragma unroll
        for (int s = 0; s < 2; ++s)
            af[s] = *(const bf16x8*)(As + (wave * 32 + s * 16 + r16) * LDT + q * 8);
#pragma unroll
        for (int j = 0; j < 4; ++j)
            bfr[j] = *(const bf16x8*)(Bs + (j * 16 + r16) * LDT + q * 8);
#pragma unroll
        for (int s = 0; s < 2; ++s)
#pragma unroll
            for (int j = 0; j < 4; ++j)
                acc[s][j] = __builtin_amdgcn_mfma_f32_16x16x32_bf16(
                    af[s], bfr[j], acc[s][j], 0, 0, 0);
    }

#pragma unroll
    for (int s = 0; s < 2; ++s) {
        const int row0 = m0 + wave * 32 + s * 16 + q * 4;
#pragma unroll
        for (int j = 0; j < 4; ++j) {
            const int col = n0 + j * 16 + r16;
            if (col < NXD) {
#pragma unroll
                for (int i = 0; i < 4; ++i)
                    atomicAdd(&xdbl[(size_t)(row0 + i) * NXD + col], acc[s][j][i]);
            }
        }
    }
}

// ---------------------------------------------------------------------------
// fused prep: x cast + 4 weight transposes + zero xdbl (for atomics)
// ---------------------------------------------------------------------------
__device__ __forceinline__ void tr_tile(
    const float* __restrict__ in, u16* __restrict__ out,
    int R, int C, int tr, int tc, int tid, float (*t)[33])
{
    const int tx = tid & 31, ty = tid >> 5;
    const int r0 = tr * 32, c0 = tc * 32;
#pragma unroll
    for (int i = 0; i < 4; ++i) {
        int r = r0 + ty + i * 8, c = c0 + tx;
        if (r < R && c < C) t[ty + i * 8][tx] = in[(size_t)r * C + c];
    }
    __syncthreads();
#pragma unroll
    for (int i = 0; i < 4; ++i) {
        int oR = c0 + ty + i * 8, oC = r0 + tx;
        if (oR < C && oC < R) out[(size_t)oR * R + oC] = f2bf(t[tx][ty + i * 8]);
    }
}

__global__ __launch_bounds__(256) void prep_kernel(
    const float* __restrict__ x,     u16* __restrict__ xbf,
    const float* __restrict__ W_in,  u16* __restrict__ winT,
    const float* __restrict__ W_out, u16* __restrict__ woutT,
    const float* __restrict__ W_x,   u16* __restrict__ wxT,
    const float* __restrict__ W_dt,  u16* __restrict__ wdtT,
    float* __restrict__ xdbl)
{
    __shared__ float t[32][33];
    const int id  = blockIdx.x;
    const int tid = threadIdx.x;
    if (id < 4096) {                                   // W_in: 1024x4096
        tr_tile(W_in, winT, 1024, 4096, id >> 7, id & 127, tid, t);
    } else if (id < 6144) {                            // W_out: 2048x1024
        int i2 = id - 4096;
        tr_tile(W_out, woutT, 2048, 1024, i2 >> 5, i2 & 31, tid, t);
    } else if (id < 6336) {                            // W_x: 2048x96
        int i3 = id - 6144;
        tr_tile(W_x, wxT, 2048, 96, i3 / 3, i3 % 3, tid, t);
    } else if (id < 6464) {                            // W_dt: 64x2048
        int i4 = id - 6336;
        tr_tile(W_dt, wdtT, 64, 2048, i4 >> 6, i4 & 63, tid, t);
    } else if (id < 14656) {                           // x cast: 2,097,152
        int i = (id - 6464) * 256 + tid;
        xbf[i] = f2bf(x[i]);
    } else {                                           // zero xdbl: 196,608 f
        f32x4 z = (f32x4){0.f, 0.f, 0.f, 0.f};
        ((f32x4*)xdbl)[(size_t)(id - 14656) * 256 + tid] = z;
    }
}

// ---------------------------------------------------------------------------
// Per-block delta tile: dl[16][256] = softplus(xdbl[rows, :64] @ W_dt + b_dt)
// M=16, N=256, K=64 via 8 MFMAs/wave. Arithmetic identical to gemm_delta.
// ---------------------------------------------------------------------------
__device__ __forceinline__ void compute_delta_tile(
    const float* __restrict__ xdbl, const u16* __restrict__ wdtT,
    const float* __restrict__ b_dt, int rowbase, int d0, int tid,
    float (*dl)[256])
{
    const int wave = tid >> 6;
    const int lane = tid & 63;
    const int q    = lane >> 4;
    const int r16  = lane & 15;

    f32x4 dacc[4];
#pragma unroll
    for (int nt = 0; nt < 4; ++nt) dacc[nt] = (f32x4){0.f, 0.f, 0.f, 0.f};

#pragma unroll
    for (int ks = 0; ks < 2; ++ks) {
        const float* ap = xdbl + (size_t)(rowbase + r16) * NXD + ks * 32 + q * 8;
        f32x4 a0 = *(const f32x4*)ap;
        f32x4 a1 = *(const f32x4*)(ap + 4);
        union { u16 u[8]; bf16x8 v; } cvt;
#pragma unroll
        for (int i = 0; i < 4; ++i) { cvt.u[i] = f2bf(a0[i]); cvt.u[4 + i] = f2bf(a1[i]); }
#pragma unroll
        for (int nt = 0; nt < 4; ++nt) {
            const u16* bp = wdtT + (size_t)(d0 + (wave * 4 + nt) * 16 + r16) * DTR + ks * 32 + q * 8;
            bf16x8 bfr = *(const bf16x8*)bp;
            dacc[nt] = __builtin_amdgcn_mfma_f32_16x16x32_bf16(
                cvt.v, bfr, dacc[nt], 0, 0, 0);
        }
    }

#pragma unroll
    for (int nt = 0; nt < 4; ++nt) {
        const int colg = (wave * 4 + nt) * 16 + r16;   // 0..255 in-block
        const float bv = b_dt[d0 + colg];
#pragma unroll
        for (int i = 0; i < 4; ++i) {
            float v = dacc[nt][i] + bv;
            v = (v > 20.f) ? v : log1pf(__expf(v));
            dl[q * 4 + i][colg] = v;
        }
    }
}

// ---------------------------------------------------------------------------
// Selective scan, 3-pass chunked, NCHUNK=64 (4 blocks/CU); prefetched loads.
// ---------------------------------------------------------------------------
__global__ __launch_bounds__(256) void scan_pass1(
    const u16* __restrict__ ucbf, const float* __restrict__ xdbl,
    const u16* __restrict__ wdtT, const float* __restrict__ b_dt,
    const float* __restrict__ A_log,
    float* __restrict__ hbuf, float* __restrict__ pbuf)
{
    __shared__ float dl[CL][256];   // 16 KB
    const int c = blockIdx.x;
    const int g = blockIdx.y;
    const int b = blockIdx.z;
    const int tid = threadIdx.x;
    const int d = g * 256 + tid;
    const int rowbase = b * L_SZ + c * CL;

    compute_delta_tile(xdbl, wdtT, b_dt, rowbase, g * 256, tid, dl);
    __syncthreads();

    float Av[16], h[16], P[16];
#pragma unroll
    for (int n = 0; n < 16; ++n) {
        Av[n] = -__expf(A_log[d * 16 + n]);
        h[n] = 0.f; P[n] = 1.f;
    }

    // prefetch row 0
    float un = bf2f(ucbf[(size_t)rowbase * DI + d]);
    f32x4 bn0 = *(const f32x4*)(xdbl + (size_t)rowbase * NXD + DTR);
    f32x4 bn1 = *(const f32x4*)(xdbl + (size_t)rowbase * NXD + DTR + 4);
    f32x4 bn2 = *(const f32x4*)(xdbl + (size_t)rowbase * NXD + DTR + 8);
    f32x4 bn3 = *(const f32x4*)(xdbl + (size_t)rowbase * NXD + DTR + 12);

    for (int i = 0; i < CL; ++i) {
        const float uu = un;
        const f32x4 b0 = bn0, b1 = bn1, b2 = bn2, b3 = bn3;
        if (i + 1 < CL) {                         // issue next row's loads now
            const int rn = rowbase + i + 1;
            un  = bf2f(ucbf[(size_t)rn * DI + d]);
            const float* xr = xdbl + (size_t)rn * NXD;
            bn0 = *(const f32x4*)(xr + DTR);
            bn1 = *(const f32x4*)(xr + DTR + 4);
            bn2 = *(const f32x4*)(xr + DTR + 8);
            bn3 = *(const f32x4*)(xr + DTR + 12);
        }
        const float dlt = dl[i][tid];
        const float du  = dlt * uu;
        const float Bv[16] = {b0.x, b0.y, b0.z, b0.w, b1.x, b1.y, b1.z, b1.w,
                              b2.x, b2.y, b2.z, b2.w, b3.x, b3.y, b3.z, b3.w};
#pragma unroll
        for (int n = 0; n < 16; ++n) {
            float e = __expf(dlt * Av[n]);
            P[n] *= e;
            h[n] = fmaf(e, h[n], du * Bv[n]);
        }
    }
    size_t base = ((size_t)((b * NCHUNK + c) * DI + d)) * 16;
#pragma unroll
    for (int n = 0; n < 16; ++n) { hbuf[base + n] = h[n]; pbuf[base + n] = P[n]; }
}

// parallel over (b, d*16+n): coalesced
__global__ __launch_bounds__(256) void scan_pass2(
    float* __restrict__ hbuf, const float* __restrict__ pbuf)
{
    const int j = blockIdx.x * 256 + threadIdx.x;   // d*16+n in [0, 32768)
    const int b = blockIdx.y;
    float h0 = 0.f;
    for (int cc = 0; cc < NCHUNK; ++cc) {
        size_t o = ((size_t)(b * NCHUNK + cc)) * (DI * 16) + j;
        float hl = hbuf[o];
        float Pl = pbuf[o];
        hbuf[o] = h0;                  // h0 entering chunk cc
        h0 = fmaf(Pl, h0, hl);
    }
}

__global__ __launch_bounds__(256) void scan_pass3(
    const u16* __restrict__ ucbf, const float* __restrict__ xdbl,
    const u16* __restrict__ wdtT, const float* __restrict__ b_dt,
    const float* __restrict__ A_log, const float* __restrict__ hbuf,
    const u16* __restrict__ xzbf, const float* __restrict__ Dskip,
    u16* __restrict__ ybf)
{
    __shared__ float dl[CL][256];   // 16 KB
    const int c = blockIdx.x;
    const int g = blockIdx.y;
    const int b = blockIdx.z;
    const int tid = threadIdx.x;
    const int d = g * 256 + tid;
    const int rowbase = b * L_SZ + c * CL;

    compute_delta_tile(xdbl, wdtT, b_dt, rowbase, g * 256, tid, dl);
    __syncthreads();

    float Av[16], h[16];
    size_t base = ((size_t)((b * NCHUNK + c) * DI + d)) * 16;
#pragma unroll
    for (int n = 0; n < 16; ++n) {
        Av[n] = -__expf(A_log[d * 16 + n]);
        h[n]  = hbuf[base + n];
    }
    const float Dk = Dskip[d];

    // prefetch row 0 (u, B row, C row, z)
    float un = bf2f(ucbf[(size_t)rowbase * DI + d]);
    float zn = bf2f(xzbf[(size_t)rowbase * (2 * DI) + DI + d]);
    f32x4 bn0 = *(const f32x4*)(xdbl + (size_t)rowbase * NXD + DTR);
    f32x4 bn1 = *(const f32x4*)(xdbl + (size_t)rowbase * NXD + DTR + 4);
    f32x4 bn2 = *(const f32x4*)(xdbl + (size_t)rowbase * NXD + DTR + 8);
    f32x4 bn3 = *(const f32x4*)(xdbl + (size_t)rowbase * NXD + DTR + 12);
    f32x4 cn0 = *(const f32x4*)(xdbl + (size_t)rowbase * NXD + DTR + DS);
    f32x4 cn1 = *(const f32x4*)(xdbl + (size_t)rowbase * NXD + DTR + DS + 4);
    f32x4 cn2 = *(const f32x4*)(xdbl + (size_t)rowbase * NXD + DTR + DS + 8);
    f32x4 cn3 = *(const f32x4*)(xdbl + (size_t)rowbase * NXD + DTR + DS + 12);

    for (int i = 0; i < CL; ++i) {
        const float uu = un, zz = zn;
        const f32x4 b0 = bn0, b1 = bn1, b2 = bn2, b3 = bn3;
        const f32x4 c0 = cn0, c1 = cn1, c2 = cn2, c3 = cn3;
        if (i + 1 < CL) {
            const int rn = rowbase + i + 1;
            un = bf2f(ucbf[(size_t)rn * DI + d]);
            zn = bf2f(xzbf[(size_t)rn * (2 * DI) + DI + d]);
            const float* xr = xdbl + (size_t)rn * NXD;
            bn0 = *(const f32x4*)(xr + DTR);
            bn1 = *(const f32x4*)(xr + DTR + 4);
            bn2 = *(const f32x4*)(xr + DTR + 8);
            bn3 = *(const f32x4*)(xr + DTR + 12);
            cn0 = *(const f32x4*)(xr + DTR + DS);
            cn1 = *(const f32x4*)(xr + DTR + DS + 4);
            cn2 = *(const f32x4*)(xr + DTR + DS + 8);
            cn3 = *(const f32x4*)(xr + DTR + DS + 12);
        }
        const float dlt = dl[i][tid];
        const float du  = dlt * uu;
        const float Bv[16] = {b0.x, b0.y, b0.z, b0.w, b1.x, b1.y, b1.z, b1.w,
                              b2.x, b2.y, b2.z, b2.w, b3.x, b3.y, b3.z, b3.w};
        const float Cv[16] = {c0.x, c0.y, c0.z, c0.w, c1.x, c1.y, c1.z, c1.w,
                              c2.x, c2.y, c2.z, c2.w, c3.x, c3.y, c3.z, c3.w};
        float y = 0.f;
#pragma unroll
        for (int n = 0; n < 16; ++n) {
            float e = __expf(dlt * Av[n]);
            h[n] = fmaf(e, h[n], du * Bv[n]);
            y = fmaf(h[n], Cv[n], y);
        }
        const int row = rowbase + i;
        float yv = fmaf(uu, Dk, y) * (zz / (1.f + __expf(-zz)));
        ybf[(size_t)row * DI + d] = f2bf(yv);
    }
}

// ---------------------------------------------------------------------------
// workspace layout (f32 element offsets) — hbuf/pbuf doubled (NCHUNK=64)
// ---------------------------------------------------------------------------
constexpr size_t OFF_XDBL    = 0;                          //   196,608 f
constexpr size_t OFF_HBUF    = OFF_XDBL + 196608;          // 4,194,304 f
constexpr size_t OFF_PBUF    = OFF_HBUF + 4194304;         // 4,194,304 f
constexpr size_t OFF_F32_END = OFF_PBUF + 4194304;
// bf16 region (u16 offsets from end of fp32 region)
constexpr size_t SOFF_XBF   = 0;                     // 2,097,152
constexpr size_t SOFF_WINT  = SOFF_XBF   + 2097152;  // 4,194,304
constexpr size_t SOFF_XZBF  = SOFF_WINT  + 4194304;  // 8,388,608
constexpr size_t SOFF_UCBF  = SOFF_XZBF  + 8388608;  // 4,194,304
constexpr size_t SOFF_WXT   = SOFF_UCBF  + 4194304;  //   196,608
constexpr size_t SOFF_WDTT  = SOFF_WXT   + 196608;   //   131,072
constexpr size_t SOFF_WOUTT = SOFF_WDTT  + 131072;   // 2,097,152
constexpr size_t SOFF_YBF   = SOFF_WOUTT + 2097152;  // 4,194,304

extern "C" void kernel_launch(void* const* d_in, const int* in_sizes, int n_in,
                              void* d_out, int out_size, void* d_ws, size_t ws_size,
                              hipStream_t stream)
{
    const float* x     = (const float*)d_in[0];
    const float* W_in  = (const float*)d_in[1];
    const float* cw    = (const float*)d_in[2];
    const float* cb    = (const float*)d_in[3];
    const float* W_x   = (const float*)d_in[4];
    const float* W_dt  = (const float*)d_in[5];
    const float* b_dt  = (const float*)d_in[6];
    const float* A_log = (const float*)d_in[7];
    const float* Dsk   = (const float*)d_in[8];
    const float* W_out = (const float*)d_in[9];
    float* out = (float*)d_out;

    float* wsf   = (float*)d_ws;
    float* xdbl  = wsf + OFF_XDBL;
    float* hbuf  = wsf + OFF_HBUF;
    float* pbuf  = wsf + OFF_PBUF;
    u16* sb    = (u16*)(wsf + OFF_F32_END);
    u16* xbf   = sb + SOFF_XBF;
    u16* winT  = sb + SOFF_WINT;
    u16* xzbf  = sb + SOFF_XZBF;
    u16* ucbf  = sb + SOFF_UCBF;
    u16* wxT   = sb + SOFF_WXT;
    u16* wdtT  = sb + SOFF_WDTT;
    u16* woutT = sb + SOFF_WOUTT;
    u16* ybf   = sb + SOFF_YBF;

    // 1) fused prep (casts, transposes, xdbl zero)
    prep_kernel<<<14848, 256, 0, stream>>>(x, xbf, W_in, winT, W_out, woutT,
                                           W_x, wxT, W_dt, wdtT, xdbl);

    // 2) xz = x @ W_in  (M=2048, N=4096, K=1024) -> bf16, XCD-swizzled
    gemm128p<<<dim3(32, 16), 256, 0, stream>>>(
        xbf, winT, nullptr, xzbf, 2048, 4096, 1024, 2);

    // 3) x_dbl = silu(conv(xz)) @ W_x — conv fused into staging; atomics to xdbl
    gemm_skinny_conv<<<dim3(2, 16, KSPLIT), 256, 0, stream>>>(
        xzbf, cw, cb, wxT, xdbl, ucbf);

    // 4) selective scan (3 launches; NCHUNK=64, delta in-block via MFMA)
    scan_pass1<<<dim3(NCHUNK, DI / 256, B_SZ), 256, 0, stream>>>(
        ucbf, xdbl, wdtT, b_dt, A_log, hbuf, pbuf);
    scan_pass2<<<dim3(DI * 16 / 256, B_SZ), 256, 0, stream>>>(hbuf, pbuf);
    scan_pass3<<<dim3(NCHUNK, DI / 256, B_SZ), 256, 0, stream>>>(
        ucbf, xdbl, wdtT, b_dt, A_log, hbuf, xzbf, Dsk, ybf);

    // 5) out = y @ W_out  (M=2048, N=1024, K=2048) — 64x64 tiles, 2 blocks/CU
    gemm_out64<<<dim3(16, 32), 256, 0, stream>>>(ybf, woutT, out, 2048, 1024, 2048);
}